// Round 11
// baseline (544.128 us; speedup 1.0000x reference)
//
#include <hip/hip_runtime.h>

// SAGE_38113539785173 — 3-layer GraphSAGE inference on MI355X (gfx950).
// Round 11: fp8-e4m3 mean-gather path.
//   Round-10 profile: k_sage is queue-saturated on random 128B row reads
//   (185MB @ ~1.75TB/s, 16 rows in flight => implied latency ~5000cyc).
//   More MLP won't help; fewer bytes will. Mean-gather rows quantized to
//   fp8 (64B/row, matrix 6.4MB ~ L2-sized); fp8 noise enters only via the
//   ~16-neighbor mean => ~0.6% effective, comparable to bf16. Self path
//   stays bf16. HW cvt_pk fp8 builtins (SW fallback included).
//   Buffers: x-buffer (dead after L0) = [B8 6.4MB | A bf16 12.8MB | A8 6.4MB];
//   B bf16 in d_out. ws unchanged ~7.2MB.
//   Tail: k_hoff merged into k_btot.

constexpr float BN_EPS = 1e-5f;

typedef __attribute__((ext_vector_type(8))) short bf16x8;
typedef __attribute__((ext_vector_type(4))) float f32x4;
typedef __attribute__((ext_vector_type(2))) float f32x2;

// ---- bf16 helpers -----------------------------------------------------------
__device__ __forceinline__ float bf2f(unsigned short u) {
  union { unsigned int i; float f; } c;
  c.i = (unsigned int)u << 16;
  return c.f;
}
__device__ __forceinline__ unsigned short f2bf(float v) {
  union { float f; unsigned int i; } c;
  c.f = v;
  unsigned int r = c.i + 0x7fffu + ((c.i >> 16) & 1u);  // round-nearest-even
  return (unsigned short)(r >> 16);
}

__device__ __forceinline__ void st_f(float* p, size_t i, float v) { p[i] = v; }
__device__ __forceinline__ void st_f(unsigned short* p, size_t i, float v) {
  p[i] = f2bf(v);
}

// ---- fp8 e4m3 helpers (HW path on gfx950; SW fallback) ----------------------
#if __has_builtin(__builtin_amdgcn_cvt_pk_f32_fp8) && \
    __has_builtin(__builtin_amdgcn_cvt_pk_fp8_f32)
#define HW_FP8 1
#endif

__device__ __forceinline__ float4 dec8(unsigned v) {
#ifdef HW_FP8
  f32x2 lo = __builtin_amdgcn_cvt_pk_f32_fp8((int)v, false);
  f32x2 hi = __builtin_amdgcn_cvt_pk_f32_fp8((int)v, true);
  float4 r;
  r.x = lo[0]; r.y = lo[1]; r.z = hi[0]; r.w = hi[1];
  return r;
#else
  auto d1 = [](unsigned b) -> float {
    unsigned s = (b & 0x80u) << 24;
    unsigned e = (b >> 3) & 15u, m = b & 7u;
    unsigned bits;
    if (e) bits = s | ((e + 120u) << 23) | (m << 20);
    else if (m) {
      int sh = (m & 4u) ? 0 : ((m & 2u) ? 1 : 2);
      bits = s | ((114u - sh) << 23) | ((m << (sh + 21)) & 0x7FFFFFu);
    } else
      bits = s;
    union { unsigned u; float f; } c;
    c.u = bits;
    return c.f;
  };
  float4 r;
  r.x = d1(v & 255u); r.y = d1((v >> 8) & 255u);
  r.z = d1((v >> 16) & 255u); r.w = d1(v >> 24);
  return r;
#endif
}

__device__ __forceinline__ unsigned enc8(float4 f) {
#ifdef HW_FP8
  int p = 0;
  p = __builtin_amdgcn_cvt_pk_fp8_f32(f.x, f.y, p, false);
  p = __builtin_amdgcn_cvt_pk_fp8_f32(f.z, f.w, p, true);
  return (unsigned)p;
#else
  auto e1 = [](float x) -> unsigned {
    union { float f; unsigned u; } c;
    c.f = x;
    unsigned s = (c.u >> 24) & 0x80u;
    float a = fabsf(x);
    if (a >= 464.f) return s | 0x7Eu;            // clamp to 448
    if (a < 0.0009765625f) {                      // denormal: q = 2^-9
      unsigned m = (unsigned)rintf(a * 512.f);
      return s | (m & 7u);
    }
    c.f = a;
    unsigned r = c.u + 0x7FFFFu + ((c.u >> 20) & 1u);  // RNE at bit 20
    unsigned e = (r >> 23) - 120u;
    unsigned m = (r >> 20) & 7u;
    if (e >= 16u || (e == 15u && m == 7u)) return s | 0x7Eu;
    return s | (e << 3) | m;
  };
  return e1(f.x) | (e1(f.y) << 8) | (e1(f.z) << 16) | (e1(f.w) << 24);
#endif
}

// row loaders: 16 lanes x (16B fp32 | 8B bf16 | 4B fp8) per 64-channel row
__device__ __forceinline__ float4 ld_row(const float* p, int row, int li) {
  return ((const float4*)p)[(size_t)row * 16 + li];
}
__device__ __forceinline__ float4 ld_row(const unsigned short* p, int row, int li) {
  ushort4 u = ((const ushort4*)p)[(size_t)row * 16 + li];
  float4 f;
  f.x = bf2f(u.x); f.y = bf2f(u.y); f.z = bf2f(u.z); f.w = bf2f(u.w);
  return f;
}
__device__ __forceinline__ float4 ld_row8(const unsigned* p, int row, int li) {
  return dec8(p[(size_t)row * 16 + li]);
}

// ------------------------------------------------- edge dtype probe (1 block)
__global__ __launch_bounds__(256) void k_probe(const int* __restrict__ w, int E,
                                               int* __restrict__ dflag) {
  __shared__ int any;
  if (threadIdx.x == 0) any = 0;
  __syncthreads();
  const int twoE = 2 * E;
  int local = 0;
  for (int i = 0; i < 8; ++i) {
    long long idx = (long long)(threadIdx.x * 8 + i) * twoE / 2048;
    int wi = (int)(idx | 1);
    if (wi < twoE && w[wi] != 0) local = 1;
  }
  if (local) atomicOr(&any, 1);
  __syncthreads();
  if (threadIdx.x == 0) *dflag = any;  // 1 => int32 edges, 0 => int64 edges
}

__device__ __forceinline__ void load_edge(const void* ei, int e, int E, int is32,
                                          int& src, int& dst) {
  if (is32) {
    const int* p = (const int*)ei;
    src = p[e];
    dst = p[E + e];
  } else {
    const long long* p = (const long long*)ei;
    src = (int)p[e];
    dst = (int)p[(long long)E + e];
  }
}

// --------------------------------- CSR phase 1: per-block bucket histograms
__global__ __launch_bounds__(256) void k_hist(const void* __restrict__ ei, int E,
                                              int N, const int* __restrict__ dflag,
                                              int NB, int chunk,
                                              int* __restrict__ hist) {
  __shared__ int h[256];
  h[threadIdx.x] = 0;
  __syncthreads();
  const int is32 = *dflag;
  int lo = blockIdx.x * chunk;
  int hi = lo + chunk;
  if (hi > E) hi = E;
  for (int e = lo + threadIdx.x; e < hi; e += 256) {
    int src, dst;
    load_edge(ei, e, E, is32, src, dst);
    if ((unsigned)src < (unsigned)N && (unsigned)dst < (unsigned)N)
      atomicAdd(&h[dst >> 9], 1);
  }
  __syncthreads();
  if (threadIdx.x < NB) hist[blockIdx.x * NB + threadIdx.x] = h[threadIdx.x];
}

// --- CSR phase 2: bucket totals + base offsets + per-(block,bucket) offsets
// (also zeroes the 256-float stats block)
__global__ __launch_bounds__(256) void k_btot(const int* __restrict__ hist,
                                              int NBLK, int NB,
                                              int* __restrict__ bucket_base,
                                              int* __restrict__ offs,
                                              float* __restrict__ stats) {
  stats[threadIdx.x] = 0.0f;
  __shared__ int part[256];
  int t = threadIdx.x;
  int s = 0;
  if (t < NB)
    for (int b = 0; b < NBLK; ++b) s += hist[b * NB + t];
  part[t] = s;
  __syncthreads();
  for (int off = 1; off < 256; off <<= 1) {
    int u = (t >= off) ? part[t - off] : 0;
    __syncthreads();
    part[t] += u;
    __syncthreads();
  }
  if (t < NB) bucket_base[t] = part[t] - s;
  if (t == NB - 1) bucket_base[NB] = part[t];
  __syncthreads();
  if (t < NB) {  // old k_hoff, coalesced across t for each b
    int carry = bucket_base[t];
    for (int b = 0; b < NBLK; ++b) {
      offs[b * NB + t] = carry;
      carry += hist[b * NB + t];
    }
  }
}

// --------------------------------- CSR phase 3: bucket-grouped scatter
__global__ __launch_bounds__(256) void k_scat(const void* __restrict__ ei, int E,
                                              int N, const int* __restrict__ dflag,
                                              int NB, int chunk,
                                              const int* __restrict__ offs,
                                              unsigned* __restrict__ csr) {
  __shared__ int cur[256];
  if (threadIdx.x < NB) cur[threadIdx.x] = offs[blockIdx.x * NB + threadIdx.x];
  __syncthreads();
  const int is32 = *dflag;
  int lo = blockIdx.x * chunk;
  int hi = lo + chunk;
  if (hi > E) hi = E;
  for (int e = lo + threadIdx.x; e < hi; e += 256) {
    int src, dst;
    load_edge(ei, e, E, is32, src, dst);
    if ((unsigned)src < (unsigned)N && (unsigned)dst < (unsigned)N) {
      int p = atomicAdd(&cur[dst >> 9], 1);
      csr[p] = ((unsigned)src << 9) | (unsigned)(dst & 511);
    }
  }
}

// --------------------------------- CSR phase 4: per-bucket fine permutation
__global__ __launch_bounds__(256) void k_fine(unsigned* __restrict__ csr,
                                              const int* __restrict__ bucket_base,
                                              int N, int* __restrict__ row_start) {
  constexpr int CAP = 12288;
  __shared__ unsigned lrec[CAP];
  __shared__ int lcnt[512];
  __shared__ int cur[512];
  __shared__ int wtot[4];
  const int b = blockIdx.x;
  const int lo = bucket_base[b];
  int cnt = bucket_base[b + 1] - lo;
  if (cnt > CAP) cnt = CAP;
  const int t = threadIdx.x;
  lcnt[t] = 0;
  lcnt[t + 256] = 0;
  __syncthreads();
  for (int i = t; i < cnt; i += 256) {
    unsigned r = csr[lo + i];
    lrec[i] = r;
    atomicAdd(&lcnt[r & 511], 1);
  }
  __syncthreads();
  int v0 = lcnt[2 * t], v1 = lcnt[2 * t + 1];
  int s = v0 + v1;
  int incl = s;
  const int lane = t & 63;
  for (int off = 1; off < 64; off <<= 1) {
    int u = __shfl_up(incl, off);
    if (lane >= off) incl += u;
  }
  const int wv = t >> 6;
  if (lane == 63) wtot[wv] = incl;
  __syncthreads();
  int woff = 0;
  for (int i = 0; i < wv; ++i) woff += wtot[i];
  int excl = woff + incl - s;
  cur[2 * t] = excl;
  cur[2 * t + 1] = excl + v0;
  int gi = b * 512 + 2 * t;
  if (gi <= N) row_start[gi] = lo + excl;
  if (gi + 1 <= N) row_start[gi + 1] = lo + excl + v0;
  __syncthreads();
  for (int i = t; i < cnt; i += 256) {
    unsigned r = lrec[i];
    int p = atomicAdd(&cur[r & 511], 1);
    csr[lo + p] = r >> 9;
  }
}

// ----------------------------------------------- bf16 -> fp8 matrix convert
__global__ __launch_bounds__(256) void k_cvt8(const unsigned short* __restrict__ src,
                                              unsigned* __restrict__ dst, int n16) {
  int i = blockIdx.x * 256 + threadIdx.x;  // one uchar4 (4 channels) per thread
  if (i >= n16) return;
  ushort4 u = ((const ushort4*)src)[i];
  float4 f;
  f.x = bf2f(u.x); f.y = bf2f(u.y); f.z = bf2f(u.z); f.w = bf2f(u.w);
  dst[i] = enc8(f);
}

// --------- fused gather-mean(+fp8) + MFMA dual matmul + BN-in + BN-out stats
template <int COUT, bool BNIN, bool BNOUT, bool FP8, typename TI, typename TO>
__global__ __launch_bounds__(256, 4) void k_sage(
    const TI* __restrict__ hin, const unsigned* __restrict__ hin8,
    const int* __restrict__ row_start, const int* __restrict__ csr,
    const float* __restrict__ Wl, const float* __restrict__ Wr,
    const float* __restrict__ bias, const float* __restrict__ statsIn,
    const float* __restrict__ gIn, const float* __restrict__ beIn,
    float* __restrict__ statsOut, TO* __restrict__ out, int n) {
  constexpr int NT = (COUT + 15) / 16;
  __shared__ short sWf[NT][4][64][8];  // B-fragments: [nt][kt][lane][j]
  __shared__ short sA[4][16][136];     // [wave][node][k: mean 0..63|self 64..127]
  __shared__ float sBN[2][64];         // BNIN: per-channel scale / shift
  __shared__ float sRed[2][4][64];     // BNOUT: per-wave channel partials

  for (int t = threadIdx.x; t < NT * 4 * 64; t += 256) {
    int lane = t & 63;
    int kt = (t >> 6) & 3;
    int nt = t >> 8;
    int kbase = kt * 32 + (lane >> 4) * 8;
    int col = nt * 16 + (lane & 15);
#pragma unroll
    for (int j = 0; j < 8; ++j) {
      int k = kbase + j;
      float wv = 0.0f;
      if (col < COUT) wv = (k < 64) ? Wl[k * COUT + col] : Wr[(k - 64) * COUT + col];
      sWf[nt][kt][lane][j] = (short)f2bf(wv);
    }
  }
  if (BNIN && threadIdx.x < 64) {
    int c = threadIdx.x;
    float inv = 1.0f / (float)n;
    float mu = statsIn[c] * inv;
    float var = statsIn[64 + c] * inv - mu * mu;
    var = var < 0.f ? 0.f : var;
    float sc = gIn[c] * rsqrtf(var + BN_EPS);
    sBN[0][c] = sc;
    sBN[1][c] = beIn[c] - mu * sc;
  }
  __syncthreads();

  const int wave = threadIdx.x >> 6;
  const int lane = threadIdx.x & 63;
  const int g = lane >> 4;
  const int li = lane & 15;
  const int quad = lane >> 4;
  const int col16 = lane & 15;

  float4 bsc = make_float4(1.f, 1.f, 1.f, 1.f);
  float4 bsh = make_float4(0.f, 0.f, 0.f, 0.f);
  if (BNIN) {
    bsc = *(const float4*)&sBN[0][li * 4];
    bsh = *(const float4*)&sBN[1][li * 4];
  }
  auto xf = [&](float4 v) -> float4 {
    if (!BNIN) return v;
    float4 r;
    r.x = fmaxf(v.x * bsc.x + bsh.x, 0.f);
    r.y = fmaxf(v.y * bsc.y + bsh.y, 0.f);
    r.z = fmaxf(v.z * bsc.z + bsh.z, 0.f);
    r.w = fmaxf(v.w * bsc.w + bsh.w, 0.f);
    return r;
  };
  // mean-path row load: fp8 matrix when FP8, else the TI matrix
  auto mrow = [&](int row) -> float4 {
    if (FP8) return ld_row8(hin8, row, li);
    return ld_row(hin, row, li);
  };

  float bias_r[NT];
#pragma unroll
  for (int nt = 0; nt < NT; ++nt) {
    int c = nt * 16 + col16;
    bias_r[nt] = (c < COUT) ? bias[c] : 0.0f;
  }

  float statS[NT], statQ[NT];
#pragma unroll
  for (int nt = 0; nt < NT; ++nt) { statS[nt] = 0.f; statQ[nt] = 0.f; }

  const int wgl = blockIdx.x * 4 + wave;
  const int nstride = gridDim.x * 64;

  for (int base = wgl * 16; base < n; base += nstride) {
#pragma unroll 1
    for (int nb = 0; nb < 16; ++nb) {
      int node = base + nb;
      if (node >= n) break;
      int rs = row_start[node];
      int re = row_start[node + 1];
      float4 acc = make_float4(0.f, 0.f, 0.f, 0.f);
      int e = rs + g;
      for (; e + 12 < re; e += 16) {  // 4 rows in flight per group, 16/wave
        int r0 = csr[e], r1 = csr[e + 4], r2 = csr[e + 8], r3 = csr[e + 12];
        float4 a = xf(mrow(r0));
        float4 b = xf(mrow(r1));
        float4 c = xf(mrow(r2));
        float4 d = xf(mrow(r3));
        acc.x += (a.x + b.x) + (c.x + d.x);
        acc.y += (a.y + b.y) + (c.y + d.y);
        acc.z += (a.z + b.z) + (c.z + d.z);
        acc.w += (a.w + b.w) + (c.w + d.w);
      }
      for (; e < re; e += 4) {
        float4 a = xf(mrow(csr[e]));
        acc.x += a.x; acc.y += a.y; acc.z += a.z; acc.w += a.w;
      }
      acc.x += __shfl_xor(acc.x, 16); acc.x += __shfl_xor(acc.x, 32);
      acc.y += __shfl_xor(acc.y, 16); acc.y += __shfl_xor(acc.y, 32);
      acc.z += __shfl_xor(acc.z, 16); acc.z += __shfl_xor(acc.z, 32);
      acc.w += __shfl_xor(acc.w, 16); acc.w += __shfl_xor(acc.w, 32);
      int deg = re - rs;
      float invd = 1.0f / (float)(deg > 0 ? deg : 1);
      float4 self = xf(ld_row(hin, node, li));  // self stays full precision
      ushort4 mv, sv;
      mv.x = f2bf(acc.x * invd); mv.y = f2bf(acc.y * invd);
      mv.z = f2bf(acc.z * invd); mv.w = f2bf(acc.w * invd);
      sv.x = f2bf(self.x); sv.y = f2bf(self.y);
      sv.z = f2bf(self.z); sv.w = f2bf(self.w);
      *(ushort4*)&sA[wave][nb][li * 4] = mv;
      *(ushort4*)&sA[wave][nb][64 + li * 4] = sv;
    }
    __builtin_amdgcn_wave_barrier();

    f32x4 acc[NT];
#pragma unroll
    for (int nt = 0; nt < NT; ++nt) acc[nt] = (f32x4){0.f, 0.f, 0.f, 0.f};
#pragma unroll
    for (int kt = 0; kt < 4; ++kt) {
      bf16x8 a = *(const bf16x8*)&sA[wave][lane & 15][kt * 32 + (lane >> 4) * 8];
#pragma unroll
      for (int nt = 0; nt < NT; ++nt) {
        bf16x8 b = *(const bf16x8*)&sWf[nt][kt][lane][0];
        acc[nt] = __builtin_amdgcn_mfma_f32_16x16x32_bf16(a, b, acc[nt], 0, 0, 0);
      }
    }
    __builtin_amdgcn_wave_barrier();

#pragma unroll
    for (int nt = 0; nt < NT; ++nt) {
      int c = nt * 16 + col16;
      if (c < COUT) {
#pragma unroll
        for (int r = 0; r < 4; ++r) {
          int node = base + quad * 4 + r;
          if (node < n) {
            float v = acc[nt][r] + bias_r[nt];
            st_f(out, (size_t)node * COUT + c, v);
            if (BNOUT) { statS[nt] += v; statQ[nt] += v * v; }
          }
        }
      }
    }
  }

  if (BNOUT) {
#pragma unroll
    for (int nt = 0; nt < NT; ++nt) {
      statS[nt] += __shfl_xor(statS[nt], 16);
      statS[nt] += __shfl_xor(statS[nt], 32);
      statQ[nt] += __shfl_xor(statQ[nt], 16);
      statQ[nt] += __shfl_xor(statQ[nt], 32);
    }
    if (quad == 0) {
#pragma unroll
      for (int nt = 0; nt < NT; ++nt) {
        sRed[0][wave][nt * 16 + col16] = statS[nt];
        sRed[1][wave][nt * 16 + col16] = statQ[nt];
      }
    }
    __syncthreads();
    if (threadIdx.x < 64) {
      int c = threadIdx.x;
      float s = sRed[0][0][c] + sRed[0][1][c] + sRed[0][2][c] + sRed[0][3][c];
      float q = sRed[1][0][c] + sRed[1][1][c] + sRed[1][2][c] + sRed[1][3][c];
      atomicAdd(&statsOut[c], s);
      atomicAdd(&statsOut[64 + c], q);
    }
  }
}

// ------------------------------------------------------------------ launcher
extern "C" void kernel_launch(void* const* d_in, const int* in_sizes, int n_in,
                              void* d_out, int out_size, void* d_ws, size_t ws_size,
                              hipStream_t stream) {
  const float* x = (const float*)d_in[0];
  const void* ei = d_in[1];
  const float* Wl0 = (const float*)d_in[2];
  const float* Wr0 = (const float*)d_in[3];
  const float* b0 = (const float*)d_in[4];
  const float* Wl1 = (const float*)d_in[5];
  const float* Wr1 = (const float*)d_in[6];
  const float* b1 = (const float*)d_in[7];
  const float* Wl2 = (const float*)d_in[8];
  const float* Wr2 = (const float*)d_in[9];
  const float* b2 = (const float*)d_in[10];
  const float* g0 = (const float*)d_in[11];
  const float* be0 = (const float*)d_in[12];
  const float* g1 = (const float*)d_in[13];
  const float* be1 = (const float*)d_in[14];

  const int N = in_sizes[0] / 64;
  const int E = in_sizes[1] / 2;
  const int NB = (N + 511) >> 9;
  const int NBLK = 256;
  const int chunk = (E + NBLK - 1) / NBLK;

  // ---- d_ws carve: ~7.2 MB ----
  char* w = (char*)d_ws;
  auto carve = [&](size_t bytes) {
    void* p = (void*)w;
    w += (bytes + 255) & ~(size_t)255;
    return p;
  };
  int* dflag = (int*)carve(4);
  float* stats = (float*)carve(1024);  // [L0: sum|sumsq][L1: sum|sumsq]
  int* row_start = (int*)carve((size_t)(N + 1) * 4);
  unsigned* csr = (unsigned*)carve((size_t)E * 4);
  int* hist = (int*)carve((size_t)NBLK * NB * 4);
  int* offs = (int*)carve((size_t)NBLK * NB * 4);
  int* bucket_base = (int*)carve((size_t)(NB + 1) * 4);

  float* statsA = stats;
  float* statsB = stats + 128;

  // feature buffers outside d_ws.
  // x buffer (25.6MB, dead after layer 0): [B8 6.4 | A bf16 12.8 | A8 6.4]
  char* xb = (char*)const_cast<float*>(x);
  unsigned short* B = (unsigned short*)d_out;            // bf16, 12.8 <= 16MB
  unsigned* B8 = (unsigned*)xb;                          // fp8, 6.4MB
  unsigned short* A = (unsigned short*)(xb + (size_t)N * 64);       // bf16
  unsigned* A8 = (unsigned*)(xb + (size_t)N * 64 * 3);              // fp8

  const int SG = 1024;  // 4 blocks/CU resident
  const int cb = (N * 16 + 255) / 256;

  // ---- CSR build (no global atomics) ----
  k_probe<<<1, 256, 0, stream>>>((const int*)ei, E, dflag);
  k_hist<<<NBLK, 256, 0, stream>>>(ei, E, N, dflag, NB, chunk, hist);
  k_btot<<<1, 256, 0, stream>>>(hist, NBLK, NB, bucket_base, offs, stats);
  k_scat<<<NBLK, 256, 0, stream>>>(ei, E, N, dflag, NB, chunk, offs, csr);
  k_fine<<<NB, 256, 0, stream>>>(csr, bucket_base, N, row_start);

  // ---- layer 0: x fp32 gather -> B bf16 (d_out); stats -> statsA ----
  k_sage<64, false, true, false, float, unsigned short><<<SG, 256, 0, stream>>>(
      x, nullptr, row_start, (const int*)csr, Wl0, Wr0, b0,
      statsA, g0, be0, statsA, B, N);
  k_cvt8<<<cb, 256, 0, stream>>>(B, B8, N * 16);

  // ---- layer 1: mean from B8 fp8, self from B bf16; -> A bf16; statsB ----
  k_sage<64, true, true, true, unsigned short, unsigned short>
      <<<SG, 256, 0, stream>>>(B, B8, row_start, (const int*)csr, Wl1, Wr1, b1,
                               statsA, g0, be0, statsB, A, N);
  k_cvt8<<<cb, 256, 0, stream>>>(A, A8, N * 16);

  // ---- layer 2: mean from A8 fp8, self from A bf16; -> d_out fp32 ----
  k_sage<40, true, false, true, unsigned short, float><<<SG, 256, 0, stream>>>(
      A, A8, row_start, (const int*)csr, Wl2, Wr2, b2,
      statsB, g1, be1, statsB, (float*)d_out, N);
}